// Round 1
// baseline (89.542 us; speedup 1.0000x reference)
//
#include <hip/hip_runtime.h>
#include <hip/hip_bf16.h>

#define N_CLASSES 256
#define DIM 128
#define M_ROWS 8192
#define S_ROWS 4096

// ---------------- accumulate per-class sums + counts ----------------
// one float4 of support per thread; atomicAdd into ws sums / counts.
__global__ __launch_bounds__(256) void proto_accum_kernel(
    const float* __restrict__ support, const int* __restrict__ labels,
    float* __restrict__ sums, float* __restrict__ cnt)
{
    int gid = blockIdx.x * 256 + threadIdx.x;       // 0 .. 4096*32-1
    int row = gid >> 5;                              // support row
    int c4  = gid & 31;                              // float4 index within row
    int lab = labels[row];
    float4 v = reinterpret_cast<const float4*>(support)[gid];
    float* dst = sums + lab * DIM + c4 * 4;
    atomicAdd(dst + 0, v.x);
    atomicAdd(dst + 1, v.y);
    atomicAdd(dst + 2, v.z);
    atomicAdd(dst + 3, v.w);
    if (c4 == 0) atomicAdd(cnt + lab, 1.0f);
}

// ---------------- distance kernel ----------------
// 64x64 output tile / block, 256 threads, 4x4 microtile, K=128 fully staged.
// Prototype = sums/max(cnt,1) computed during B staging.
// LDS layout: [64][128] f32, 16B chunks XOR-swizzled by (row>>2)&7.
__global__ __launch_bounds__(256) void dist_kernel(
    const float* __restrict__ x,
    const float* __restrict__ sums, const float* __restrict__ cnt,
    float* __restrict__ out)
{
    __shared__ float As[64 * DIM];
    __shared__ float Bs[64 * DIM];

    const int t  = threadIdx.x;
    const int bm = blockIdx.x;   // 0..127  (x-row tiles)
    const int bn = blockIdx.y;   // 0..3    (class tiles)

    // ---- stage A: 64 rows x 128 cols = 2048 float4, 8 per thread ----
    const float4* x4 = reinterpret_cast<const float4*>(x + (size_t)bm * 64 * DIM);
    #pragma unroll
    for (int it = 0; it < 8; ++it) {
        int l  = t + it * 256;           // 0..2047
        int r  = l >> 5;
        int c4 = l & 31;
        float4 v = x4[l];
        int swz = c4 ^ ((r >> 2) & 7);
        *reinterpret_cast<float4*>(As + r * DIM + swz * 4) = v;
    }

    // ---- stage B: prototypes for classes bn*64 .. bn*64+63, with division ----
    #pragma unroll
    for (int it = 0; it < 8; ++it) {
        int l  = t + it * 256;
        int c  = l >> 5;                 // class within tile
        int c4 = l & 31;
        int cls = bn * 64 + c;
        float4 v = *reinterpret_cast<const float4*>(sums + cls * DIM + c4 * 4);
        float inv = 1.0f / fmaxf(cnt[cls], 1.0f);
        v.x *= inv; v.y *= inv; v.z *= inv; v.w *= inv;
        int swz = c4 ^ ((c >> 2) & 7);
        *reinterpret_cast<float4*>(Bs + c * DIM + swz * 4) = v;
    }

    __syncthreads();

    const int tx = t & 15, ty = t >> 4;
    const int r0 = ty * 4, c0 = tx * 4;

    float acc[4][4] = {};

    #pragma unroll 4
    for (int k4 = 0; k4 < 32; ++k4) {
        float4 a[4], b[4];
        #pragma unroll
        for (int i = 0; i < 4; ++i) {
            int r = r0 + i;
            a[i] = *reinterpret_cast<const float4*>(As + r * DIM + ((k4 ^ ((r >> 2) & 7)) * 4));
        }
        #pragma unroll
        for (int j = 0; j < 4; ++j) {
            int c = c0 + j;
            b[j] = *reinterpret_cast<const float4*>(Bs + c * DIM + ((k4 ^ ((c >> 2) & 7)) * 4));
        }
        #pragma unroll
        for (int i = 0; i < 4; ++i) {
            #pragma unroll
            for (int j = 0; j < 4; ++j) {
                float d0 = a[i].x - b[j].x;
                float d1 = a[i].y - b[j].y;
                float d2 = a[i].z - b[j].z;
                float d3 = a[i].w - b[j].w;
                acc[i][j] = fmaf(d0, d0, acc[i][j]);
                acc[i][j] = fmaf(d1, d1, acc[i][j]);
                acc[i][j] = fmaf(d2, d2, acc[i][j]);
                acc[i][j] = fmaf(d3, d3, acc[i][j]);
            }
        }
    }

    // ---- write out: out[(bm*64+r)*256 + bn*64 + c0 .. +3] ----
    #pragma unroll
    for (int i = 0; i < 4; ++i) {
        int gr = bm * 64 + r0 + i;
        float4 o;
        o.x = -acc[i][0]; o.y = -acc[i][1]; o.z = -acc[i][2]; o.w = -acc[i][3];
        *reinterpret_cast<float4*>(out + (size_t)gr * N_CLASSES + bn * 64 + c0) = o;
    }
}

extern "C" void kernel_launch(void* const* d_in, const int* in_sizes, int n_in,
                              void* d_out, int out_size, void* d_ws, size_t ws_size,
                              hipStream_t stream) {
    const float* x       = (const float*)d_in[0];   // 8192*128
    const float* support = (const float*)d_in[1];   // 4096*128
    const int*   labels  = (const int*)d_in[2];     // 4096
    float* out = (float*)d_out;                     // 8192*256

    float* sums = (float*)d_ws;                     // 256*128
    float* cnt  = sums + N_CLASSES * DIM;           // 256

    // ws is poisoned 0xAA before every timed call -> zero it each launch.
    hipMemsetAsync(d_ws, 0, (N_CLASSES * DIM + N_CLASSES) * sizeof(float), stream);

    // accumulate class sums/counts
    proto_accum_kernel<<<dim3((S_ROWS * (DIM / 4)) / 256), 256, 0, stream>>>(
        support, labels, sums, cnt);

    // fused prototype-finalize + distance
    dist_kernel<<<dim3(M_ROWS / 64, N_CLASSES / 64), 256, 0, stream>>>(
        x, sums, cnt, out);
}